// Round 8
// baseline (1103.210 us; speedup 1.0000x reference)
//
#include <hip/hip_runtime.h>

#define S_LEN 512
#define BSZ 8
#define NH 8
#define HD 64
#define IN_DIM 512
#define PROJ 2576   // NH*(5*HD+2)
#define SEG 322     // per-head: 5*64+2
#define AST 200     // act row stride in f32: q64,k64,rk64,beta,rbeta

typedef __attribute__((ext_vector_type(8))) __bf16 bf16x8;
typedef __attribute__((ext_vector_type(4))) float f32x4;

static __device__ __forceinline__ unsigned short f2bf(float f) {
  unsigned u = __float_as_uint(f);
  unsigned r = (u + 0x7fffu + ((u >> 16) & 1u)) >> 16;
  return (unsigned short)r;
}
static __device__ __forceinline__ float bf2f(unsigned short s) {
  return __uint_as_float(((unsigned)s) << 16);
}

// ---------------- LayerNorm: x (4096x512 f32) -> normed bf16 ----------------
__global__ __launch_bounds__(256) void ln_kernel(const float* __restrict__ x,
                                                 const float* __restrict__ gamma,
                                                 const float* __restrict__ beta,
                                                 unsigned short* __restrict__ out) {
  int wave = threadIdx.x >> 6, lane = threadIdx.x & 63;
  int row = blockIdx.x * 4 + wave;
  const float* xr = x + (size_t)row * IN_DIM + lane * 8;
  float4 a = *(const float4*)xr;
  float4 b = *(const float4*)(xr + 4);
  float vals[8] = {a.x, a.y, a.z, a.w, b.x, b.y, b.z, b.w};
  float s = 0.f, ss = 0.f;
#pragma unroll
  for (int i = 0; i < 8; i++) { s += vals[i]; ss += vals[i] * vals[i]; }
#pragma unroll
  for (int o = 32; o; o >>= 1) { s += __shfl_xor(s, o); ss += __shfl_xor(ss, o); }
  float mu = s * (1.f / 512.f);
  float var = ss * (1.f / 512.f) - mu * mu;
  float rstd = rsqrtf(var + 1e-5f);
  const float* g = gamma + lane * 8;
  const float* be = beta + lane * 8;
  float4 g1 = *(const float4*)g, g2 = *(const float4*)(g + 4);
  float4 b1 = *(const float4*)be, b2 = *(const float4*)(be + 4);
  float gs[8] = {g1.x, g1.y, g1.z, g1.w, g2.x, g2.y, g2.z, g2.w};
  float bs[8] = {b1.x, b1.y, b1.z, b1.w, b2.x, b2.y, b2.z, b2.w};
  union { unsigned short u[8]; uint4 v; } pk;
#pragma unroll
  for (int i = 0; i < 8; i++) pk.u[i] = f2bf((vals[i] - mu) * rstd * gs[i] + bs[i]);
  *(uint4*)(out + (size_t)row * IN_DIM + lane * 8) = pk.v;
}

// ---------------- fused f32 -> bf16 cast of both weight matrices ----------------
__global__ void cast2_kernel(const float* __restrict__ in1, unsigned short* __restrict__ out1, int n1,
                             const float* __restrict__ in2, unsigned short* __restrict__ out2, int n2) {
  int i = blockIdx.x * blockDim.x + threadIdx.x;
  int st = gridDim.x * blockDim.x;
  for (int j = i; j < n1; j += st) out1[j] = f2bf(in1[j]);
  for (int j = i; j < n2; j += st) out2[j] = f2bf(in2[j]);
}

// ---------------- GEMM: C[m][n] = sum_k A[m][k]*B[n][k] (both bf16, K-contig) ----------------
template <int BF16_OUT, int RESID>
__global__ __launch_bounds__(256) void gemm_bt(const unsigned short* __restrict__ A,
                                               const unsigned short* __restrict__ B,
                                               void* __restrict__ Cout,
                                               const float* __restrict__ resid,
                                               int M, int N, int K) {
  __shared__ __align__(16) unsigned short As[64][40];
  __shared__ __align__(16) unsigned short Bs[64][40];
  int tid = threadIdx.x;
  int lane = tid & 63, wave = tid >> 6;
  int m0 = blockIdx.y * 64, n0 = blockIdx.x * 64;
  int srow = tid >> 2, skq = (tid & 3) * 8;
  const unsigned short* Ap = A + (size_t)(m0 + srow) * K + skq;
  const unsigned short* Bp = B + (size_t)(n0 + srow) * K + skq;
  bool bvalid = (n0 + srow) < N;
  f32x4 zero = {0.f, 0.f, 0.f, 0.f};
  f32x4 acc[4];
#pragma unroll
  for (int nt = 0; nt < 4; nt++) acc[nt] = zero;
  int q = lane >> 4, m16 = lane & 15;
  for (int k0 = 0; k0 < K; k0 += 32) {
    uint4 av = *(const uint4*)(Ap + k0);
    uint4 bz = {0u, 0u, 0u, 0u};
    uint4 bv = bvalid ? *(const uint4*)(Bp + k0) : bz;
    *(uint4*)&As[srow][skq] = av;
    *(uint4*)&Bs[srow][skq] = bv;
    __syncthreads();
    bf16x8 af = *(const bf16x8*)&As[wave * 16 + m16][q * 8];
#pragma unroll
    for (int nt = 0; nt < 4; nt++) {
      bf16x8 bfv = *(const bf16x8*)&Bs[nt * 16 + m16][q * 8];
      acc[nt] = __builtin_amdgcn_mfma_f32_16x16x32_bf16(af, bfv, acc[nt], 0, 0, 0);
    }
    __syncthreads();
  }
  int rbase = q * 4;
#pragma unroll
  for (int nt = 0; nt < 4; nt++) {
#pragma unroll
    for (int rr = 0; rr < 4; rr++) {
      int gm = m0 + wave * 16 + rbase + rr;
      int gn = n0 + nt * 16 + m16;
      if (gn < N) {
        float v = acc[nt][rr];
        if (BF16_OUT) {
          ((unsigned short*)Cout)[(size_t)gm * N + gn] = f2bf(v);
        } else {
          float o = v;
          if (RESID) o += resid[(size_t)gm * N + gn];
          ((float*)Cout)[(size_t)gm * N + gn] = o;
        }
      }
    }
  }
}

// ---------------- parallel activations: softmax(q,k,rk), sigmoid(betas) -> f32 ----------------
__global__ __launch_bounds__(256) void act_kernel(const unsigned short* __restrict__ qkvb,
                                                  float* __restrict__ act) {
  int gw = blockIdx.x * 4 + (threadIdx.x >> 6);
  int l = threadIdx.x & 63;
  int m = gw >> 3, hh = gw & 7;
  int t = m >> 3, b = m & 7;
  const unsigned short* src = qkvb + (size_t)m * PROJ + hh * SEG;
  float fq = bf2f(src[l]);
  float fk = bf2f(src[64 + l]);
  float fr = bf2f(src[192 + l]);
  float mq = fq, mk = fk, mr = fr;
#pragma unroll
  for (int o = 32; o; o >>= 1) {
    mq = fmaxf(mq, __shfl_xor(mq, o));
    mk = fmaxf(mk, __shfl_xor(mk, o));
    mr = fmaxf(mr, __shfl_xor(mr, o));
  }
  float eq = __expf(fq - mq), ek = __expf(fk - mk), er = __expf(fr - mr);
  float sq = eq, sk = ek, sr = er;
#pragma unroll
  for (int o = 32; o; o >>= 1) {
    sq += __shfl_xor(sq, o);
    sk += __shfl_xor(sk, o);
    sr += __shfl_xor(sr, o);
  }
  int bh = b * 8 + hh;
  float* dst = act + ((size_t)bh * S_LEN + t) * AST;
  dst[l] = eq * __builtin_amdgcn_rcpf(sq);
  dst[64 + l] = ek * __builtin_amdgcn_rcpf(sk);
  dst[128 + l] = er * __builtin_amdgcn_rcpf(sr);
  if (l < 2) {
    float xv = bf2f(src[320 + l]);
    dst[192 + l] = __builtin_amdgcn_rcpf(1.f + __expf(-xv));
  }
}

// ---------------- scan1: independent W-scan (z) and R-scan (u), 1 wave per block ----------------
// Block 2*bh   : delta-rule W-scan  -> z[bh][t][l]  (needs q,k,beta,v)
// Block 2*bh+1 : delta-rule R-scan  -> u[bh][t][l] = rbeta*(rv - R.rk)[l]  (needs rk,rbeta,rv)
// One wave per CU: private DS pipe, zero barriers (same-wave DS is in-order).
__global__ __launch_bounds__(64, 1) void scan1_kernel(const unsigned short* __restrict__ qkvb,
                                                      const float* __restrict__ act,
                                                      float* __restrict__ zbuf,
                                                      float* __restrict__ ubuf) {
  int blk = blockIdx.x;
  int kind = blk & 1;   // 0 = W-scan, 1 = R-scan
  int bh = blk >> 1;
  int b = bh >> 3, hh = bh & 7;
  int l = threadIdx.x;

  __shared__ __align__(16) float s0v[2][64];  // k (W) / rk (R)
  __shared__ __align__(16) float s1v[2][64];  // q (W only)

  const float* arow = act + (size_t)bh * S_LEN * AST;
  const unsigned short* vsrc = qkvb + (size_t)b * PROJ + hh * SEG + (kind ? 256 : 128);
  const size_t ts = (size_t)BSZ * PROJ;
  float* obuf = (kind ? ubuf : zbuf) + (size_t)bh * S_LEN * 64;
  int aoff = kind ? 128 : 64;   // vector operand offset in act row (k or rk)

  f32x4 M[16];
#pragma unroll
  for (int j = 0; j < 16; j++) M[j] = (f32x4){0.f, 0.f, 0.f, 0.f};

  // stage t=0; stage regs hold act rows t+1..t+3 (depth 4);
  // cb/cvu regs hold beta/v rows t..t+2 (depth 3 -> refill from row t+3)
  s0v[0][l] = arow[aoff + l];
  if (kind == 0) s1v[0][l] = arow[l];
  float pA0, pA1, pB0, pB1, pC0, pC1;
  float cb0, cb1, cb2;
  {
    const float* r1 = arow + AST;
    const float* r2 = arow + 2 * AST;
    const float* r3 = arow + 3 * AST;
    pA0 = r1[aoff + l]; pB0 = r2[aoff + l]; pC0 = r3[aoff + l];
    if (kind == 0) { pA1 = r1[l]; pB1 = r2[l]; pC1 = r3[l]; }
    else { pA1 = pB1 = pC1 = 0.f; }
    cb0 = arow[192 + kind]; cb1 = r1[192 + kind]; cb2 = r2[192 + kind];
  }
  unsigned short cvu0 = vsrc[l];
  unsigned short cvu1 = vsrc[ts + l];
  unsigned short cvu2 = vsrc[2 * ts + l];

  for (int t = 0; t < S_LEN; t++) {
    int buf = t & 1, nslot = buf ^ 1;
    // stage t+1 (pA loaded 3 bodies ago); same-wave in-order DS, no barrier
    s0v[nslot][l] = pA0;
    if (kind == 0) s1v[nslot][l] = pA1;
    // prefetch act row t+4 (stage depth 4); beta/v row t+3 (reg depth 3)
    int t4 = (t + 4 < S_LEN) ? (t + 4) : (S_LEN - 1);
    int t3 = (t + 3 < S_LEN) ? (t + 3) : (S_LEN - 1);
    const float* r4 = arow + (size_t)t4 * AST;
    float pN0 = r4[aoff + l];
    float pN1 = (kind == 0) ? r4[l] : 0.f;
    float pbN = arow[(size_t)t3 * AST + 192 + kind];  // FIX: row t+3, not t+4
    unsigned short cvuN = vsrc[(size_t)t3 * ts + l];

    float cv = bf2f(cvu0);
    float bt = cb0;
    const f32x4* s4a = (const f32x4*)s0v[buf];

    // matvec1: vold = M . (k|rk)   (operand cached in kk across both loops)
    f32x4 kk[16];
    f32x4 a0 = {0.f, 0.f, 0.f, 0.f}, a1 = a0, a2 = a0, a3 = a0;
#pragma unroll
    for (int j = 0; j < 16; j += 4) {
      kk[j] = s4a[j];         a0 += M[j] * kk[j];
      kk[j + 1] = s4a[j + 1]; a1 += M[j + 1] * kk[j + 1];
      kk[j + 2] = s4a[j + 2]; a2 += M[j + 2] * kk[j + 2];
      kk[j + 3] = s4a[j + 3]; a3 += M[j + 3] * kk[j + 3];
    }
    f32x4 vo = (a0 + a1) + (a2 + a3);
    float vold = (vo.x + vo.y) + (vo.z + vo.w);
    float coef = bt * (cv - vold);
    f32x4 c4 = {coef, coef, coef, coef};

    if (kind == 0) {
      // W: update + z = M.q
      const f32x4* s4q = (const f32x4*)s1v[buf];
      a0 = a1 = a2 = a3 = (f32x4){0.f, 0.f, 0.f, 0.f};
#pragma unroll
      for (int j = 0; j < 16; j += 4) {
        M[j] += c4 * kk[j];          a0 += M[j] * s4q[j];
        M[j + 1] += c4 * kk[j + 1];  a1 += M[j + 1] * s4q[j + 1];
        M[j + 2] += c4 * kk[j + 2];  a2 += M[j + 2] * s4q[j + 2];
        M[j + 3] += c4 * kk[j + 3];  a3 += M[j + 3] * s4q[j + 3];
      }
      f32x4 zo = (a0 + a1) + (a2 + a3);
      obuf[t * 64 + l] = (zo.x + zo.y) + (zo.z + zo.w);
    } else {
      // R: update only; emit u_t[l] = coef
#pragma unroll
      for (int j = 0; j < 16; j += 4) {
        M[j] += c4 * kk[j];
        M[j + 1] += c4 * kk[j + 1];
        M[j + 2] += c4 * kk[j + 2];
        M[j + 3] += c4 * kk[j + 3];
      }
      obuf[t * 64 + l] = coef;
    }

    pA0 = pB0; pA1 = pB1;
    pB0 = pC0; pB1 = pC1;
    pC0 = pN0; pC1 = pN1;
    cb0 = cb1; cb1 = cb2; cb2 = pbN;
    cvu0 = cvu1; cvu1 = cvu2; cvu2 = cvuN;
  }
}

// ---------------- scan2: minimal serial h-recurrence ----------------
// Rebuilds R from (u, rk) — both prefetchable, independent of h — then the only
// truly serial chain: h -> eh (LDS round trip) -> hp = R.eh -> h. Zero barriers.
__global__ __launch_bounds__(64, 1) void scan2_kernel(const float* __restrict__ act,
                                                      const float* __restrict__ zbuf,
                                                      const float* __restrict__ ubuf,
                                                      unsigned short* __restrict__ hs) {
  int bh = blockIdx.x;
  int b = bh >> 3, hh = bh & 7;
  int l = threadIdx.x;

  __shared__ __align__(16) float s0v[2][64];  // rk stage
  __shared__ __align__(16) float ehb[64];

  const float* arow = act + (size_t)bh * S_LEN * AST;
  const float* zrow = zbuf + (size_t)bh * S_LEN * 64;
  const float* urow = ubuf + (size_t)bh * S_LEN * 64;

  f32x4 M[16];
#pragma unroll
  for (int j = 0; j < 16; j++) M[j] = (f32x4){0.f, 0.f, 0.f, 0.f};
  ehb[l] = 1.f;  // softmax(h0=0): eh=1; sum folds naturally

  s0v[0][l] = arow[128 + l];
  float pA0 = arow[AST + 128 + l];
  float pB0 = arow[2 * AST + 128 + l];
  float pC0 = arow[3 * AST + 128 + l];
  float zc0 = zrow[l], zc1 = zrow[64 + l], zc2 = zrow[128 + l];
  float uc0 = urow[l], uc1 = urow[64 + l], uc2 = urow[128 + l];

  unsigned short* hdst = hs + (size_t)b * 512 + hh * 64 + l;

  for (int t = 0; t < S_LEN; t++) {
    int buf = t & 1, nslot = buf ^ 1;
    s0v[nslot][l] = pA0;
    int t4 = (t + 4 < S_LEN) ? (t + 4) : (S_LEN - 1);
    int t3 = (t + 3 < S_LEN) ? (t + 3) : (S_LEN - 1);
    float pN0 = arow[(size_t)t4 * AST + 128 + l];
    float zN = zrow[t3 * 64 + l];
    float uN = urow[t3 * 64 + l];

    // R update: M += u_t[l] * rk_t  (independent of h -> off the serial path)
    f32x4 c4 = {uc0, uc0, uc0, uc0};
    const f32x4* s4a = (const f32x4*)s0v[buf];
#pragma unroll
    for (int j = 0; j < 16; j += 4) {
      M[j] += c4 * s4a[j];
      M[j + 1] += c4 * s4a[j + 1];
      M[j + 2] += c4 * s4a[j + 2];
      M[j + 3] += c4 * s4a[j + 3];
    }

    // serial core: hp = M.eh, sm = sum(eh)
    const f32x4* e4 = (const f32x4*)ehb;
    f32x4 a0 = {0.f, 0.f, 0.f, 0.f}, a1 = a0, a2 = a0, a3 = a0;
    f32x4 s0 = a0, s1 = a0, s2 = a0, s3 = a0;
#pragma unroll
    for (int j = 0; j < 16; j += 4) {
      f32x4 e0 = e4[j], e1 = e4[j + 1], e2 = e4[j + 2], e3 = e4[j + 3];
      a0 += M[j] * e0;      s0 += e0;
      a1 += M[j + 1] * e1;  s1 += e1;
      a2 += M[j + 2] * e2;  s2 += e2;
      a3 += M[j + 3] * e3;  s3 += e3;
    }
    f32x4 ho = (a0 + a1) + (a2 + a3);
    f32x4 so = (s0 + s1) + (s2 + s3);
    float hp = (ho.x + ho.y) + (ho.z + ho.w);
    float sm = (so.x + so.y) + (so.z + so.w);
    float h = zc0 + hp * __builtin_amdgcn_rcpf(sm);
    hdst[(size_t)t * BSZ * 512] = f2bf(h);
    ehb[l] = __expf(h - 20.f);  // shift-invariant; read next body (same-wave in-order)

    pA0 = pB0; pB0 = pC0; pC0 = pN0;
    zc0 = zc1; zc1 = zc2; zc2 = zN;
    uc0 = uc1; uc1 = uc2; uc2 = uN;
  }
}

extern "C" void kernel_launch(void* const* d_in, const int* in_sizes, int n_in,
                              void* d_out, int out_size, void* d_ws, size_t ws_size,
                              hipStream_t stream) {
  const float* x = (const float*)d_in[0];
  const float* W_slow = (const float*)d_in[1];
  const float* W_out = (const float*)d_in[2];
  const float* gamma = (const float*)d_in[3];
  const float* beta = (const float*)d_in[4];

  char* ws = (char*)d_ws;
  size_t off = 0;
  unsigned short* normed = (unsigned short*)(ws + off); off += (size_t)4096 * 512 * 2;
  unsigned short* Wslow_b = (unsigned short*)(ws + off); off += (size_t)PROJ * 512 * 2;
  unsigned short* Wout_b = (unsigned short*)(ws + off); off += (size_t)512 * 512 * 2;
  unsigned short* qkvb = (unsigned short*)(ws + off); off += (size_t)4096 * PROJ * 2;
  float* act = (float*)(ws + off); off += (size_t)64 * S_LEN * AST * 4;
  float* zbuf = (float*)(ws + off); off += (size_t)64 * S_LEN * 64 * 4;
  float* ubuf = (float*)(ws + off); off += (size_t)64 * S_LEN * 64 * 4;
  unsigned short* hsb = normed;  // normed is dead after gemm1; reuse for hs

  hipLaunchKernelGGL(ln_kernel, dim3(1024), dim3(256), 0, stream, x, gamma, beta, normed);
  hipLaunchKernelGGL(cast2_kernel, dim3(512), dim3(256), 0, stream,
                     W_slow, Wslow_b, PROJ * 512, W_out, Wout_b, 512 * 512);
  hipLaunchKernelGGL((gemm_bt<1, 0>), dim3((PROJ + 63) / 64, 4096 / 64), dim3(256), 0, stream,
                     normed, Wslow_b, (void*)qkvb, (const float*)nullptr, 4096, PROJ, 512);
  hipLaunchKernelGGL(act_kernel, dim3(8192), dim3(256), 0, stream, qkvb, act);
  hipLaunchKernelGGL(scan1_kernel, dim3(128), dim3(64), 0, stream, qkvb, act, zbuf, ubuf);
  hipLaunchKernelGGL(scan2_kernel, dim3(64), dim3(64), 0, stream, act, zbuf, ubuf, hsb);
  hipLaunchKernelGGL((gemm_bt<0, 1>), dim3(512 / 64, 4096 / 64), dim3(256), 0, stream,
                     hsb, Wout_b, d_out, x, 4096, 512, 512);
}